// Round 11
// baseline (254.834 us; speedup 1.0000x reference)
//
#include <hip/hip_runtime.h>
#include <math.h>

#define NN 8192
#define DIM 128
#define NG 512                        // 16-row strips
#define NCT 128                       // 64-col tiles per row
#define NITEMS (NG * 16)              // 8192 (strip, phase) work items
#define NBLOCKS 768
#define NWT (NBLOCKS * 4)             // 3072 waves
#define REPB 4
#define REPD 4

typedef short bf16x8 __attribute__((ext_vector_type(8)));
typedef float f32x4 __attribute__((ext_vector_type(4)));

__device__ inline unsigned short f2bf(float x) {
    unsigned u = __float_as_uint(x);
    unsigned r = u + 0x7FFFu + ((u >> 16) & 1u);  // RNE
    return (unsigned short)(r >> 16);
}

// ---------------------------------------------------------------------------
// Kernel 0: pack mapping into MFMA-fragment-order bf16 chunks (1KB/wave-load).
// ---------------------------------------------------------------------------
__global__ void pack_kernel(const float* __restrict__ m, unsigned short* __restrict__ buf2) {
    const int t = threadIdx.x, l = t & 63;
    const int W = blockIdx.x * 4 + (t >> 6);
    const int g = W >> 2, kq = W & 3;
    const int row = g * 16 + (l & 15);
    const int k0 = kq * 32 + (l >> 4) * 8;
    const float* src = m + (size_t)row * DIM + k0;
    float4 v0 = *reinterpret_cast<const float4*>(src);
    float4 v1 = *reinterpret_cast<const float4*>(src + 4);
    float f[8] = {v0.x, v0.y, v0.z, v0.w, v1.x, v1.y, v1.z, v1.w};
    union { ushort4 u4[2]; unsigned short us[8]; } o;
#pragma unroll
    for (int q = 0; q < 8; ++q) o.us[q] = f2bf(f[q]);
    unsigned short* dst = buf2 + (size_t)W * 512 + l * 8;
    *reinterpret_cast<ushort4*>(dst) = o.u4[0];
    *reinterpret_cast<ushort4*>(dst + 4) = o.u4[1];
}

// ---------------------------------------------------------------------------
// Kernel 1: exact fp32 row norms
// ---------------------------------------------------------------------------
__global__ void sq_kernel(const float* __restrict__ mapping, float* __restrict__ sq) {
    int i = blockIdx.x * blockDim.x + threadIdx.x;
    if (i < NN) {
        const float4* row = reinterpret_cast<const float4*>(mapping + (size_t)i * DIM);
        float s = 0.f;
#pragma unroll
        for (int q = 0; q < DIM / 4; ++q) {
            float4 v = row[q];
            s += v.x * v.x + v.y * v.y + v.z * v.z + v.w * v.w;
        }
        sq[i] = s;
    }
}

// ---------------------------------------------------------------------------
// Kernel 2: r9 fused kernel, unchanged (the validated real path).
// ---------------------------------------------------------------------------
__global__ __launch_bounds__(256, 3) void dist_kernel(const unsigned short* __restrict__ buf2,
                                                      const float* __restrict__ D,
                                                      const float* __restrict__ sq,
                                                      float* __restrict__ partials) {
    const int t = threadIdx.x, l = t & 63;
    const int W = blockIdx.x * 4 + (t >> 6);
    const int l15 = l & 15;
    const int colq = (l >> 4) * 4;

    int item = W;
    while (item < NITEMS) {
        const int g = item >> 4, p = item & 15;
        int cj = (g >> 2) + p;
        if (cj >= NCT) {
            if (l == 0) partials[item] = 0.f;
            item += NWT;
            continue;
        }
        const int i_row = g * 16 + l15;
        const int cdiag = g >> 2;

        bf16x8 af[4];
#pragma unroll
        for (int kq = 0; kq < 4; ++kq)
            af[kq] = *(const bf16x8*)(buf2 + (size_t)(g * 4 + kq) * 512 + l * 8);
        const float sa = sq[i_row];

        f32x4 dc[4], sbc[4];
#pragma unroll
        for (int s = 0; s < 4; ++s) {
            dc[s] = *reinterpret_cast<const f32x4*>(D + (size_t)i_row * NN + cj * 64 + s * 16 + colq);
            sbc[s] = *reinterpret_cast<const f32x4*>(sq + cj * 64 + s * 16 + colq);
        }

        float psum = 0.f;
        for (; cj < NCT; cj += 16) {
            const int ncj = cj + 16;
            bf16x8 bfr[4][4];
#pragma unroll
            for (int s = 0; s < 4; ++s)
#pragma unroll
                for (int kq = 0; kq < 4; ++kq)
                    bfr[s][kq] = *(const bf16x8*)(buf2 + (size_t)((cj * 4 + s) * 4 + kq) * 512 + l * 8);

            f32x4 dn[4], sbn[4];
            if (ncj < NCT) {
#pragma unroll
                for (int s = 0; s < 4; ++s) {
                    dn[s] = *reinterpret_cast<const f32x4*>(D + (size_t)i_row * NN + ncj * 64 + s * 16 + colq);
                    sbn[s] = *reinterpret_cast<const f32x4*>(sq + ncj * 64 + s * 16 + colq);
                }
            }

#pragma unroll
            for (int s = 0; s < 4; ++s) {
                f32x4 acc = {};
#pragma unroll
                for (int kq = 0; kq < 4; ++kq)
                    acc = __builtin_amdgcn_mfma_f32_16x16x32_bf16(bfr[s][kq], af[kq], acc, 0, 0, 0);
                if (cj != cdiag) {
#pragma unroll
                    for (int r = 0; r < 4; ++r) {
                        float d2 = fmaf(-2.f, acc[r], sa + sbc[s][r]);
                        float d = sqrtf(fmaxf(d2, 0.f));
                        float Dv = dc[s][r];
                        psum += __fdividef(fabsf(d - Dv), Dv);
                    }
                } else {
#pragma unroll
                    for (int r = 0; r < 4; ++r) {
                        const int j = cj * 64 + s * 16 + colq + r;
                        if (j > i_row) {
                            float d2 = fmaf(-2.f, acc[r], sa + sbc[s][r]);
                            float d = sqrtf(fmaxf(d2, 0.f));
                            float Dv = dc[s][r];
                            psum += __fdividef(fabsf(d - Dv), Dv);
                        }
                    }
                }
            }
            if (ncj < NCT) {
#pragma unroll
                for (int s = 0; s < 4; ++s) { dc[s] = dn[s]; sbc[s] = sbn[s]; }
            }
        }

        for (int off = 32; off > 0; off >>= 1) psum += __shfl_down(psum, off, 64);
        if (l == 0) partials[item] = 2.f * psum;
        item += NWT;
    }
}

// ---------------------------------------------------------------------------
// DIAG B: B-fragment loads + MFMA only, same schedule/concurrency, REPB reps
// (phase rotated per rep to defeat CSE). No D traffic at all.
// ---------------------------------------------------------------------------
__global__ __launch_bounds__(256, 3) void diagB_kernel(const unsigned short* __restrict__ buf2,
                                                       float* __restrict__ dummy) {
    const int t = threadIdx.x, l = t & 63;
    const int W = blockIdx.x * 4 + (t >> 6);
    float keep = 0.f;

    for (int rep = 0; rep < REPB; ++rep) {
        for (int item = W; item < NITEMS; item += NWT) {
            const int g = item >> 4, p = (item + rep) & 15;
            int cj = (g >> 2) + p;
            if (cj >= NCT) continue;

            bf16x8 af[4];
#pragma unroll
            for (int kq = 0; kq < 4; ++kq)
                af[kq] = *(const bf16x8*)(buf2 + (size_t)(g * 4 + kq) * 512 + l * 8);

            f32x4 acc[4] = {};
            for (; cj < NCT; cj += 16) {
                bf16x8 bfr[4][4];
#pragma unroll
                for (int s = 0; s < 4; ++s)
#pragma unroll
                    for (int kq = 0; kq < 4; ++kq)
                        bfr[s][kq] = *(const bf16x8*)(buf2 + (size_t)((cj * 4 + s) * 4 + kq) * 512 + l * 8);
#pragma unroll
                for (int s = 0; s < 4; ++s)
#pragma unroll
                    for (int kq = 0; kq < 4; ++kq)
                        acc[s] = __builtin_amdgcn_mfma_f32_16x16x32_bf16(bfr[s][kq], af[kq], acc[s], 0, 0, 0);
            }
            keep += acc[0][0] + acc[1][1] + acc[2][2] + acc[3][3];
        }
    }
    for (int off = 32; off > 0; off >>= 1) keep += __shfl_down(keep, off, 64);
    if (l == 0) dummy[W] = keep;
}

// ---------------------------------------------------------------------------
// DIAG D: exact r9 D+sqb gather shape (16 rows x 64B per inst, 1-deep
// prefetch, strip-phase order), no B/MFMA. REPD reps, phase rotated.
// ---------------------------------------------------------------------------
__global__ __launch_bounds__(256, 3) void diagD_kernel(const float* __restrict__ D,
                                                       const float* __restrict__ sq,
                                                       float* __restrict__ dummy) {
    const int t = threadIdx.x, l = t & 63;
    const int W = blockIdx.x * 4 + (t >> 6);
    const int l15 = l & 15;
    const int colq = (l >> 4) * 4;
    float keep = 0.f;

    for (int rep = 0; rep < REPD; ++rep) {
        for (int item = W; item < NITEMS; item += NWT) {
            const int g = item >> 4, p = (item + rep) & 15;
            int cj = (g >> 2) + p;
            if (cj >= NCT) continue;
            const int i_row = g * 16 + l15;

            f32x4 dc[4], sbc[4];
#pragma unroll
            for (int s = 0; s < 4; ++s) {
                dc[s] = *reinterpret_cast<const f32x4*>(D + (size_t)i_row * NN + cj * 64 + s * 16 + colq);
                sbc[s] = *reinterpret_cast<const f32x4*>(sq + cj * 64 + s * 16 + colq);
            }
            for (; cj < NCT; cj += 16) {
                const int ncj = cj + 16;
                f32x4 dn[4], sbn[4];
                if (ncj < NCT) {
#pragma unroll
                    for (int s = 0; s < 4; ++s) {
                        dn[s] = *reinterpret_cast<const f32x4*>(D + (size_t)i_row * NN + ncj * 64 + s * 16 + colq);
                        sbn[s] = *reinterpret_cast<const f32x4*>(sq + ncj * 64 + s * 16 + colq);
                    }
                }
#pragma unroll
                for (int s = 0; s < 4; ++s) {
                    keep += dc[s][0] + dc[s][1] + dc[s][2] + dc[s][3];
                    keep += sbc[s][0] - sbc[s][3];
                }
                if (ncj < NCT) {
#pragma unroll
                    for (int s = 0; s < 4; ++s) { dc[s] = dn[s]; sbc[s] = sbn[s]; }
                }
            }
        }
    }
    for (int off = 32; off > 0; off >>= 1) keep += __shfl_down(keep, off, 64);
    if (l == 0) dummy[W] = keep;
}

// ---------------------------------------------------------------------------
// Kernel 3: deterministic final reduction over item partials
// ---------------------------------------------------------------------------
__global__ void reduce_kernel(const float* __restrict__ partials, float* __restrict__ out) {
    __shared__ double sm[256];
    const int t = threadIdx.x;
    double s = 0.0;
    for (int i = t; i < NITEMS; i += 256) s += (double)partials[i];
    sm[t] = s;
    __syncthreads();
    for (int off = 128; off > 0; off >>= 1) {
        if (t < off) sm[t] += sm[t + off];
        __syncthreads();
    }
    if (t == 0) out[0] = (float)(sm[0] / ((double)NN * (double)NN - (double)NN));
}

// ---------------------------------------------------------------------------
extern "C" void kernel_launch(void* const* d_in, const int* in_sizes, int n_in,
                              void* d_out, int out_size, void* d_ws, size_t ws_size,
                              hipStream_t stream) {
    const float* mapping = (const float*)d_in[0];
    const float* D       = (const float*)d_in[1];
    float* out = (float*)d_out;

    unsigned short* buf2 = (unsigned short*)d_ws;        // NN*DIM bf16 = 2 MiB
    float* sq            = (float*)(buf2 + NN * DIM);    // NN floats
    float* partials      = sq + NN;                      // NITEMS floats
    float* dummyB        = partials + NITEMS;            // NWT floats
    float* dummyD        = dummyB + NWT;                 // NWT floats

    pack_kernel<<<512, 256, 0, stream>>>(mapping, buf2);
    sq_kernel<<<NN / 256, 256, 0, stream>>>(mapping, sq);
    dist_kernel<<<NBLOCKS, 256, 0, stream>>>(buf2, D, sq, partials);
    reduce_kernel<<<1, 256, 0, stream>>>(partials, out);
    // ---- diagnostics (results discarded; bench cost accepted this round) ----
    diagB_kernel<<<NBLOCKS, 256, 0, stream>>>(buf2, dummyB);
    diagD_kernel<<<NBLOCKS, 256, 0, stream>>>(D, sq, dummyD);
}

// Round 12
// 91.022 us; speedup vs baseline: 2.7997x; 2.7997x over previous
//
#include <hip/hip_runtime.h>
#include <math.h>

#define NN 8192
#define DIM 128
#define NQ 128
#define NP 16
#define NBLK (NQ * NP)   // 2048 blocks = 8 XCD chunks x 256

typedef short bf16x8 __attribute__((ext_vector_type(8)));
typedef float f32x4 __attribute__((ext_vector_type(4)));

__device__ inline void gload_lds16(const void* g, void* l) {
    __builtin_amdgcn_global_load_lds((const __attribute__((address_space(1))) void*)g,
                                     (__attribute__((address_space(3))) void*)l, 16, 0, 0);
}

__device__ inline unsigned short f2bf(float x) {
    unsigned u = __float_as_uint(x);
    unsigned r = u + 0x7FFFu + ((u >> 16) & 1u);  // RNE
    return (unsigned short)(r >> 16);
}

// ---------------------------------------------------------------------------
// Kernel 0: pack mapping into MFMA-fragment-order bf16 chunks (1KB/wave-load).
// Chunk (tile16 g, kq): lane l's 16B at chunk*1024 + l*16.
// ---------------------------------------------------------------------------
__global__ void pack_kernel(const float* __restrict__ m, unsigned short* __restrict__ buf2) {
    const int t = threadIdx.x, l = t & 63;
    const int W = blockIdx.x * 4 + (t >> 6);
    const int g = W >> 2, kq = W & 3;
    const int row = g * 16 + (l & 15);
    const int k0 = kq * 32 + (l >> 4) * 8;
    const float* src = m + (size_t)row * DIM + k0;
    float4 v0 = *reinterpret_cast<const float4*>(src);
    float4 v1 = *reinterpret_cast<const float4*>(src + 4);
    float f[8] = {v0.x, v0.y, v0.z, v0.w, v1.x, v1.y, v1.z, v1.w};
    union { ushort4 u4[2]; unsigned short us[8]; } o;
#pragma unroll
    for (int q = 0; q < 8; ++q) o.us[q] = f2bf(f[q]);
    unsigned short* dst = buf2 + (size_t)W * 512 + l * 8;
    *reinterpret_cast<ushort4*>(dst) = o.u4[0];
    *reinterpret_cast<ushort4*>(dst + 4) = o.u4[1];
}

// ---------------------------------------------------------------------------
// Kernel 1: exact fp32 row norms
// ---------------------------------------------------------------------------
__global__ void sq_kernel(const float* __restrict__ mapping, float* __restrict__ sq) {
    int i = blockIdx.x * blockDim.x + threadIdx.x;
    if (i < NN) {
        const float4* row = reinterpret_cast<const float4*>(mapping + (size_t)i * DIM);
        float s = 0.f;
#pragma unroll
        for (int q = 0; q < DIM / 4; ++q) {
            float4 v = row[q];
            s += v.x * v.x + v.y * v.y + v.z * v.z + v.w * v.w;
        }
        sq[i] = s;
    }
}

// ---------------------------------------------------------------------------
// Kernel 2: block=(q,p): rows 64q..64q+63 (wave w: strip 4q+w), cols walk
// cj=q+p,+16,.. <128. B tile (16KB) staged ONCE per block into double-buffered
// LDS via global_load_lds; consumed via ds_read (lgkmcnt channel). Per-wave
// vmem FIFO holds ONLY [stage | D | sqb] groups with counted vmcnt + raw
// s_barrier (no drains): D(t) gets a full step of slack, stage(t+1)/D(t+1)
// stay in flight through compute. Named register double-buffer for D.
// ---------------------------------------------------------------------------
__global__ __launch_bounds__(256, 4) void dist_kernel(const unsigned short* __restrict__ buf2,
                                                      const float* __restrict__ D,
                                                      const float* __restrict__ sq,
                                                      float* __restrict__ partials) {
    __shared__ __align__(16) unsigned short ldsb[2][8192];  // 2 x 16KB
    __shared__ float wred[4];

    const int t = threadIdx.x, l = t & 63, w = t >> 6;
    const int b = blockIdx.x;
    const int nb = (b & 7) * (NBLK / 8) + (b >> 3);  // bijective XCD-chunked swizzle
    const int q = nb >> 4, p = nb & 15;
    const int cj0 = q + p;

    float psum = 0.f;

    if (cj0 < 128) {
        const int nt = (128 - cj0 + 15) >> 4;
        const int l15 = l & 15, colq = (l >> 4) * 4;
        const int i_row = q * 64 + w * 16 + l15;

        // A fragments (once per block) + sqa
        bf16x8 af[4];
#pragma unroll
        for (int kq = 0; kq < 4; ++kq)
            af[kq] = *(const bf16x8*)(buf2 + (size_t)(((q * 4 + w) * 4) + kq) * 512 + l * 8);
        const float sa = sq[i_row];

        // prologue: stage(0) -> ldsb[0], D(0) -> dcA
        f32x4 dcA[4], dcB[4];
#pragma unroll
        for (int kq = 0; kq < 4; ++kq)
            gload_lds16(buf2 + (size_t)((cj0 * 4 + w) * 4 + kq) * 512 + l * 8,
                        (void*)&ldsb[0][(w * 4 + kq) * 512]);
#pragma unroll
        for (int s = 0; s < 4; ++s)
            dcA[s] = *(const f32x4*)(D + (size_t)i_row * NN + cj0 * 64 + s * 16 + colq);

        auto step = [&](int tt, f32x4(&dc)[4], f32x4(&dn)[4], int cur) {
            const int cj = cj0 + tt * 16;
            const bool more = (tt + 1 < nt);

            // sqb(t) (L2-hot), then stage(t+1)+D(t+1) — FIFO: newest stay in flight
            f32x4 sbc[4];
#pragma unroll
            for (int s = 0; s < 4; ++s)
                sbc[s] = *(const f32x4*)(sq + cj * 64 + s * 16 + colq);
            if (more) {
                const int ncj = cj + 16;
#pragma unroll
                for (int kq = 0; kq < 4; ++kq)
                    gload_lds16(buf2 + (size_t)((ncj * 4 + w) * 4 + kq) * 512 + l * 8,
                                (void*)&ldsb[cur ^ 1][(w * 4 + kq) * 512]);
#pragma unroll
                for (int s = 0; s < 4; ++s)
                    dn[s] = *(const f32x4*)(D + (size_t)i_row * NN + ncj * 64 + s * 16 + colq);
            }
            __builtin_amdgcn_sched_barrier(0);
            // wait: stage(t) complete; leave [D(t), sqb(t), stage(t+1), D(t+1)]
            if (more) asm volatile("s_waitcnt vmcnt(16)" ::: "memory");
            else      asm volatile("s_waitcnt vmcnt(8)" ::: "memory");
            __builtin_amdgcn_s_barrier();

            // B(t) via ds_read (lgkmcnt) + MFMA
            f32x4 acc[4];
#pragma unroll
            for (int s = 0; s < 4; ++s) {
                bf16x8 bfr[4];
#pragma unroll
                for (int kq = 0; kq < 4; ++kq)
                    bfr[kq] = *(const bf16x8*)&ldsb[cur][(s * 4 + kq) * 512 + l * 8];
                f32x4 a = {};
#pragma unroll
                for (int kq = 0; kq < 4; ++kq)
                    a = __builtin_amdgcn_mfma_f32_16x16x32_bf16(bfr[kq], af[kq], a, 0, 0, 0);
                acc[s] = a;
            }
            asm volatile("s_waitcnt lgkmcnt(0)" ::: "memory");
            __builtin_amdgcn_sched_barrier(0);
            __builtin_amdgcn_s_barrier();  // buf(t) free for overwrite next step

            // epilogue (compiler inserts counted vmcnt for dc/sbc; leaves
            // stage(t+1)/D(t+1) outstanding)
            if (cj != q) {
#pragma unroll
                for (int s = 0; s < 4; ++s)
#pragma unroll
                    for (int r = 0; r < 4; ++r) {
                        float d2 = fmaf(-2.f, acc[s][r], sa + sbc[s][r]);
                        float d = sqrtf(fmaxf(d2, 0.f));
                        float Dv = dc[s][r];
                        psum += __fdividef(fabsf(d - Dv), Dv);
                    }
            } else {
#pragma unroll
                for (int s = 0; s < 4; ++s)
#pragma unroll
                    for (int r = 0; r < 4; ++r) {
                        const int j = cj * 64 + s * 16 + colq + r;
                        if (j > i_row) {
                            float d2 = fmaf(-2.f, acc[s][r], sa + sbc[s][r]);
                            float d = sqrtf(fmaxf(d2, 0.f));
                            float Dv = dc[s][r];
                            psum += __fdividef(fabsf(d - Dv), Dv);
                        }
                    }
            }
        };

        for (int tt = 0; tt < nt; tt += 2) {
            step(tt, dcA, dcB, 0);
            if (tt + 1 < nt) step(tt + 1, dcB, dcA, 1);
        }
    }

    // deterministic block reduction (upper-tri sum; x2 at write)
    for (int off = 32; off > 0; off >>= 1) psum += __shfl_down(psum, off, 64);
    __syncthreads();
    if (l == 0) wred[w] = psum;
    __syncthreads();
    if (t == 0) partials[b] = 2.f * ((wred[0] + wred[1]) + (wred[2] + wred[3]));
}

// ---------------------------------------------------------------------------
// Kernel 3: deterministic final reduction
// ---------------------------------------------------------------------------
__global__ void reduce_kernel(const float* __restrict__ partials, float* __restrict__ out) {
    __shared__ double sm[256];
    const int t = threadIdx.x;
    double s = 0.0;
    for (int i = t; i < NBLK; i += 256) s += (double)partials[i];
    sm[t] = s;
    __syncthreads();
    for (int off = 128; off > 0; off >>= 1) {
        if (t < off) sm[t] += sm[t + off];
        __syncthreads();
    }
    if (t == 0) out[0] = (float)(sm[0] / ((double)NN * (double)NN - (double)NN));
}

// ---------------------------------------------------------------------------
extern "C" void kernel_launch(void* const* d_in, const int* in_sizes, int n_in,
                              void* d_out, int out_size, void* d_ws, size_t ws_size,
                              hipStream_t stream) {
    const float* mapping = (const float*)d_in[0];
    const float* D       = (const float*)d_in[1];
    float* out = (float*)d_out;

    unsigned short* buf2 = (unsigned short*)d_ws;        // NN*DIM bf16 = 2 MiB
    float* sq            = (float*)(buf2 + NN * DIM);    // NN floats
    float* partials      = sq + NN;                      // NBLK floats

    pack_kernel<<<512, 256, 0, stream>>>(mapping, buf2);
    sq_kernel<<<NN / 256, 256, 0, stream>>>(mapping, sq);
    dist_kernel<<<NBLK, 256, 0, stream>>>(buf2, D, sq, partials);
    reduce_kernel<<<1, 256, 0, stream>>>(partials, out);
}

// Round 13
// 69.334 us; speedup vs baseline: 3.6754x; 1.3128x over previous
//
#include <hip/hip_runtime.h>
#include <math.h>

#define NN 8192
#define DIM 128
#define NBLK 2048   // (q 0..127) x (p 0..15)

typedef short bf16x8 __attribute__((ext_vector_type(8)));
typedef float f32x4 __attribute__((ext_vector_type(4)));

__device__ inline unsigned short f2bf(float x) {
    unsigned u = __float_as_uint(x);
    unsigned r = u + 0x7FFFu + ((u >> 16) & 1u);  // RNE
    return (unsigned short)(r >> 16);
}
__device__ inline float bf2f(unsigned short h) {
    return __uint_as_float(((unsigned)h) << 16);
}

// ---------------------------------------------------------------------------
// Kernel 0: pack mapping into MFMA-fragment-order bf16 chunks (1KB/wave-load).
// ---------------------------------------------------------------------------
__global__ void pack_kernel(const float* __restrict__ m, unsigned short* __restrict__ buf2) {
    const int t = threadIdx.x, l = t & 63;
    const int W = blockIdx.x * 4 + (t >> 6);
    const int g = W >> 2, kq = W & 3;
    const int row = g * 16 + (l & 15);
    const int k0 = kq * 32 + (l >> 4) * 8;
    const float* src = m + (size_t)row * DIM + k0;
    float4 v0 = *reinterpret_cast<const float4*>(src);
    float4 v1 = *reinterpret_cast<const float4*>(src + 4);
    float f[8] = {v0.x, v0.y, v0.z, v0.w, v1.x, v1.y, v1.z, v1.w};
    union { ushort4 u4[2]; unsigned short us[8]; } o;
#pragma unroll
    for (int q = 0; q < 8; ++q) o.us[q] = f2bf(f[q]);
    unsigned short* dst = buf2 + (size_t)W * 512 + l * 8;
    *reinterpret_cast<ushort4*>(dst) = o.u4[0];
    *reinterpret_cast<ushort4*>(dst + 4) = o.u4[1];
}

// ---------------------------------------------------------------------------
// Kernel 1: exact fp32 row norms
// ---------------------------------------------------------------------------
__global__ void sq_kernel(const float* __restrict__ mapping, float* __restrict__ sq) {
    int i = blockIdx.x * blockDim.x + threadIdx.x;
    if (i < NN) {
        const float4* row = reinterpret_cast<const float4*>(mapping + (size_t)i * DIM);
        float s = 0.f;
#pragma unroll
        for (int q = 0; q < DIM / 4; ++q) {
            float4 v = row[q];
            s += v.x * v.x + v.y * v.y + v.z * v.z + v.w * v.w;
        }
        sq[i] = s;
    }
}

// ---------------------------------------------------------------------------
// Kernel 2: PRODUCER/CONSUMER wave specialization. Block (q,p): rows
// 64q..64q+63, 64-col tiles cj = q+p, +16, ... Waves 0-3 (producers): B-frag
// L2 loads + MFMA + sqrt -> bf16 d-tile into 2-slot LDS ring. Waves 4-7
// (consumers): ONLY D loads in their vmem FIFO (pure HBM stream, 1-tile-deep
// named double buffer) + ds_read d-tile + ratio accumulate. Raw s_barrier per
// slot (no __syncthreads in loop -> D prefetch survives barriers).
// ---------------------------------------------------------------------------
__global__ __launch_bounds__(512, 4) void dist_kernel(const unsigned short* __restrict__ buf2,
                                                      const float* __restrict__ D,
                                                      const float* __restrict__ sq,
                                                      float* __restrict__ partials) {
    __shared__ __align__(16) char dtile[2][64 * 144];  // bf16 d, 144B row pitch
    __shared__ float wred[8];

    const int t = threadIdx.x, l = t & 63, w = t >> 6;
    const int b = blockIdx.x;
    const int q = b >> 4, p = b & 15;
    const int cj0 = q + p;
    float psum = 0.f;

    if (cj0 < 128) {
        const int nt = (128 - cj0 + 15) >> 4;
        const int l15 = l & 15, hi = l >> 4;
        const int colq = hi * 4;
        const int strip = w & 3;
        const int i_row = q * 64 + strip * 16 + l15;
        const int ldsoff = (strip * 16 + l15) * 144 + hi * 8;  // + s*32

        if (w < 4) {
            // ========================= PRODUCER =========================
            bf16x8 af[4];
#pragma unroll
            for (int kq = 0; kq < 4; ++kq)
                af[kq] = *(const bf16x8*)(buf2 + (size_t)((q * 4 + strip) * 4 + kq) * 512 + l * 8);
            const float sa = sq[i_row];

            for (int tt = 0; tt < nt; ++tt) {
                const int cj = cj0 + tt * 16;
                char* slot = &dtile[tt & 1][0];
#pragma unroll
                for (int s = 0; s < 4; ++s) {
                    bf16x8 bfr[4];
#pragma unroll
                    for (int kq = 0; kq < 4; ++kq)
                        bfr[kq] = *(const bf16x8*)(buf2 + (size_t)((cj * 4 + s) * 4 + kq) * 512 + l * 8);
                    f32x4 sb = *(const f32x4*)(sq + cj * 64 + s * 16 + colq);
                    f32x4 acc = {};
#pragma unroll
                    for (int kq = 0; kq < 4; ++kq)
                        acc = __builtin_amdgcn_mfma_f32_16x16x32_bf16(bfr[kq], af[kq], acc, 0, 0, 0);
                    ushort4 o;
                    unsigned short* op = (unsigned short*)&o;
#pragma unroll
                    for (int r = 0; r < 4; ++r) {
                        float d2 = fmaf(-2.f, acc[r], sa + sb[r]);
                        op[r] = f2bf(sqrtf(fmaxf(d2, 0.f)));
                    }
                    *reinterpret_cast<ushort4*>(slot + ldsoff + s * 32) = o;
                }
                asm volatile("s_waitcnt lgkmcnt(0)" ::: "memory");
                __builtin_amdgcn_sched_barrier(0);
                __builtin_amdgcn_s_barrier();
            }
        } else {
            // ========================= CONSUMER =========================
            const float* Drow = D + (size_t)i_row * NN;

            auto consume = [&](int tile, const f32x4(&dc)[4]) {
                const int cj = cj0 + tile * 16;
                const char* slot = &dtile[tile & 1][0];
                if (cj != q) {
#pragma unroll
                    for (int s = 0; s < 4; ++s) {
                        ushort4 o = *reinterpret_cast<const ushort4*>(slot + ldsoff + s * 32);
                        const unsigned short* op = (const unsigned short*)&o;
#pragma unroll
                        for (int r = 0; r < 4; ++r) {
                            float Dv = dc[s][r];
                            psum += __fdividef(fabsf(bf2f(op[r]) - Dv), Dv);
                        }
                    }
                } else {
#pragma unroll
                    for (int s = 0; s < 4; ++s) {
                        ushort4 o = *reinterpret_cast<const ushort4*>(slot + ldsoff + s * 32);
                        const unsigned short* op = (const unsigned short*)&o;
#pragma unroll
                        for (int r = 0; r < 4; ++r) {
                            const int j = cj * 64 + s * 16 + colq + r;
                            if (j > i_row) {
                                float Dv = dc[s][r];
                                psum += __fdividef(fabsf(bf2f(op[r]) - Dv), Dv);
                            }
                        }
                    }
                }
            };

            f32x4 dA[4], dB[4];
#pragma unroll
            for (int s = 0; s < 4; ++s)
                dA[s] = *(const f32x4*)(Drow + cj0 * 64 + s * 16 + colq);
            __builtin_amdgcn_s_barrier();

            bool cur_a = true;
            for (int tt = 1; tt < nt; ++tt) {
                const int cj = cj0 + tt * 16;
                if (cur_a) {
#pragma unroll
                    for (int s = 0; s < 4; ++s)
                        dB[s] = *(const f32x4*)(Drow + cj * 64 + s * 16 + colq);
                    consume(tt - 1, dA);
                } else {
#pragma unroll
                    for (int s = 0; s < 4; ++s)
                        dA[s] = *(const f32x4*)(Drow + cj * 64 + s * 16 + colq);
                    consume(tt - 1, dB);
                }
                cur_a = !cur_a;
                __builtin_amdgcn_s_barrier();
            }
            if (cur_a) consume(nt - 1, dA);
            else       consume(nt - 1, dB);
        }
    }

    // ---- deterministic block reduction (8 waves; producers contribute 0) ----
    for (int off = 32; off > 0; off >>= 1) psum += __shfl_down(psum, off, 64);
    __syncthreads();
    if (l == 0) wred[w] = psum;
    __syncthreads();
    if (t == 0) {
        float s = 0.f;
#pragma unroll
        for (int k = 0; k < 8; ++k) s += wred[k];
        partials[b] = 2.f * s;
    }
}

// ---------------------------------------------------------------------------
// Kernel 3: deterministic final reduction
// ---------------------------------------------------------------------------
__global__ void reduce_kernel(const float* __restrict__ partials, float* __restrict__ out) {
    __shared__ double sm[256];
    const int t = threadIdx.x;
    double s = 0.0;
    for (int i = t; i < NBLK; i += 256) s += (double)partials[i];
    sm[t] = s;
    __syncthreads();
    for (int off = 128; off > 0; off >>= 1) {
        if (t < off) sm[t] += sm[t + off];
        __syncthreads();
    }
    if (t == 0) out[0] = (float)(sm[0] / ((double)NN * (double)NN - (double)NN));
}

// ---------------------------------------------------------------------------
extern "C" void kernel_launch(void* const* d_in, const int* in_sizes, int n_in,
                              void* d_out, int out_size, void* d_ws, size_t ws_size,
                              hipStream_t stream) {
    const float* mapping = (const float*)d_in[0];
    const float* D       = (const float*)d_in[1];
    float* out = (float*)d_out;

    unsigned short* buf2 = (unsigned short*)d_ws;        // NN*DIM bf16 = 2 MiB
    float* sq            = (float*)(buf2 + NN * DIM);    // NN floats
    float* partials      = sq + NN;                      // NBLK floats

    pack_kernel<<<512, 256, 0, stream>>>(mapping, buf2);
    sq_kernel<<<NN / 256, 256, 0, stream>>>(mapping, sq);
    dist_kernel<<<NBLK, 512, 0, stream>>>(buf2, D, sq, partials);
    reduce_kernel<<<1, 256, 0, stream>>>(partials, out);
}